// Round 8
// baseline (151.720 us; speedup 1.0000x reference)
//
#include <hip/hip_runtime.h>
#include <hip/hip_bf16.h>

#define KDIM 1024
#define NDIM 1024
#define NEXP 8
#define TTOK 8192
#define NTILE_IDS (72 * 8)   // worst-case m-tiles x n-tiles; invalid ids decode to no-op

typedef __bf16 bf16x8 __attribute__((ext_vector_type(8)));
typedef __bf16 bf16x4 __attribute__((ext_vector_type(4)));
typedef float  f32x4  __attribute__((ext_vector_type(4)));

__device__ __forceinline__ void gl2lds16(const void* g, void* l) {
  __builtin_amdgcn_global_load_lds(
      (const __attribute__((address_space(1))) void*)g,
      (__attribute__((address_space(3))) void*)l, 16, 0, 0);
}

// Fragment-swizzled layouts (16B per lane-slot):
//   swA slot(panel,kt,lane) = x[panel*16 + (lane&15)][kt*32 + (lane>>4)*8 .. +8]
//   swB slot(e,panel,kt,lane) = W[e][kt*32 + (lane>>4)*8 .. +8][panel*16 + (lane&15)]

// ---------------- prepass: build swA/swB + zero the work-queue counter ----------------
__global__ __launch_bounds__(256) void prepass(
    const float* __restrict__ x, const float* __restrict__ W,
    __bf16* __restrict__ swA, __bf16* __restrict__ swB, int* __restrict__ ctr)
{
  __shared__ __align__(16) __bf16 Lt[64 * 72];
  const int t = threadIdx.x;
  if (blockIdx.x == 0 && t == 0) *ctr = 0;   // stream-ordered before the gemm
  if (blockIdx.x < 1024) {
#pragma unroll
    for (int p = 0; p < 4; ++p) {
      int s = blockIdx.x * 1024 + p * 256 + t;
      int lane = s & 63, kt = (s >> 6) & 31, panel = s >> 11;
      int row = panel * 16 + (lane & 15);
      int k0 = kt * 32 + ((lane >> 4) << 3);
      const float* xp = x + (size_t)row * KDIM + k0;
      float4 a = *(const float4*)xp;
      float4 b = *(const float4*)(xp + 4);
      bf16x8 v;
      v[0] = (__bf16)a.x; v[1] = (__bf16)a.y; v[2] = (__bf16)a.z; v[3] = (__bf16)a.w;
      v[4] = (__bf16)b.x; v[5] = (__bf16)b.y; v[6] = (__bf16)b.z; v[7] = (__bf16)b.w;
      *(bf16x8*)(swA + (size_t)s * 8) = v;
    }
  } else {
    int bid = blockIdx.x - 1024;
    int e = bid >> 8, r = bid & 255;
    int k0 = (r >> 4) * 64, n0 = (r & 15) * 64;
    const float* Wp = W + (size_t)e * KDIM * NDIM;
    int rr0 = t >> 4, c4 = t & 15;
#pragma unroll
    for (int p = 0; p < 4; ++p) {
      int kk = rr0 + p * 16;
      float4 v = *(const float4*)(Wp + (size_t)(k0 + kk) * NDIM + n0 + c4 * 4);
      Lt[(c4 * 4 + 0) * 72 + kk] = (__bf16)v.x;
      Lt[(c4 * 4 + 1) * 72 + kk] = (__bf16)v.y;
      Lt[(c4 * 4 + 2) * 72 + kk] = (__bf16)v.z;
      Lt[(c4 * 4 + 3) * 72 + kk] = (__bf16)v.w;
    }
    __syncthreads();
#pragma unroll
    for (int q = 0; q < 2; ++q) {
      int slot = q * 256 + t;
      int lane = slot & 63, grp = slot >> 6;
      int np = grp & 3, kt2 = grp >> 2;
      int nl = np * 16 + (lane & 15);
      int kl = kt2 * 32 + ((lane >> 4) << 3);
      bf16x8 v = *(const bf16x8*)(Lt + nl * 72 + kl);
      int panel = (n0 >> 4) + np;
      int ktg = (k0 >> 5) + kt2;
      size_t sg = (((size_t)e * 64 + panel) * 32 + ktg) * 64 + lane;
      *(bf16x8*)(swB + sg * 8) = v;
    }
  }
}

// ------- persistent GEMM: work-queue balanced, LDS broadcast, vmcnt(4) pipeline -------
// 512 blocks (2/CU) pull tile ids from a device-scope atomic; dynamic balancing
// removes the 2.25-blocks/CU 1.33x tail of the static 576-block grid.
// Per tile: 3-stage LDS pipeline, per-wave `s_waitcnt vmcnt(4)` + raw s_barrier
// (never drains the in-flight prefetch). The tile-top __syncthreads() doubles as
// the WAR guard on the LDS buffers between consecutive tiles.
__global__ __launch_bounds__(256, 2) void moe_gemm_persist(
    const __bf16* __restrict__ swA, const __bf16* __restrict__ swB,
    const int* __restrict__ gs, const float* __restrict__ bias,
    float* __restrict__ out, int* __restrict__ ctr)
{
  __shared__ __align__(16) __bf16 buf[3][8192];   // 3 x 16 KB (A slots 0..511, B 512..1023)
  __shared__ int tile_sh;

  const int t = threadIdx.x, lane = t & 63, wv = t >> 6;
  const int wm = wv & 1, wn = wv >> 1, lm = lane & 15, lg = lane >> 4;

  for (;;) {
    if (t == 0) tile_sh = atomicAdd(ctr, 1);
    __syncthreads();                         // broadcast id + WAR guard on buf[]
    const int id = tile_sh;
    if (id >= NTILE_IDS) break;              // block-uniform exit
    const int n0 = (id & 7) * 128;
    const int y = id >> 3;

    int e = 0, tile0 = 0, lo = 0, hi = 0, found = 0, off = 0;
    int yy = y;
#pragma unroll
    for (int i = 0; i < NEXP; ++i) {
      int g = gs[i];
      int first = off >> 7;
      int cnt = (g > 0) ? (((off + g - 1) >> 7) - first + 1) : 0;
      if (!found) {
        if (yy < cnt) {
          found = 1; e = i; tile0 = (first + yy) << 7;
          lo = max(tile0, off); hi = min(tile0 + 128, off + g);
        } else yy -= cnt;
      }
      off += g;
    }
    if (!found) continue;                    // block-uniform: no barrier divergence

    // staging sources: wave wv stages A panels {wv, 4+wv} and B panels {wv, 4+wv}
    const __bf16* gA0 = swA + (size_t)((tile0 >> 4) + wv) * 16384 + lane * 8;
    const __bf16* gA1 = swA + (size_t)((tile0 >> 4) + 4 + wv) * 16384 + lane * 8;
    const __bf16* gB0 = swB + (size_t)(e * 64 + (n0 >> 4) + wv) * 16384 + lane * 8;
    const __bf16* gB1 = swB + (size_t)(e * 64 + (n0 >> 4) + 4 + wv) * 16384 + lane * 8;

    auto stage = [&](int kt, int sb) {
      __bf16* l = &buf[sb][0];
      const int ko = kt * 512;
      gl2lds16(gA0 + ko, l + (size_t)(0 * 256 + wv * 64) * 8);
      gl2lds16(gA1 + ko, l + (size_t)(1 * 256 + wv * 64) * 8);
      gl2lds16(gB0 + ko, l + (size_t)(2 * 256 + wv * 64) * 8);
      gl2lds16(gB1 + ko, l + (size_t)(3 * 256 + wv * 64) * 8);
    };

    f32x4 acc[4][4] = {};
    auto compute = [&](const __bf16* l) {
      bf16x8 aF[4], bF[4];
#pragma unroll
      for (int i = 0; i < 4; ++i)
        aF[i] = *(const bf16x8*)(l + (size_t)((wm * 4 + i) * 64 + lane) * 8);
#pragma unroll
      for (int j = 0; j < 4; ++j)
        bF[j] = *(const bf16x8*)(l + 4096 + (size_t)((wn * 4 + j) * 64 + lane) * 8);
#pragma unroll
      for (int i = 0; i < 4; ++i)
#pragma unroll
        for (int j = 0; j < 4; ++j)
          acc[i][j] = __builtin_amdgcn_mfma_f32_16x16x32_bf16(aF[i], bF[j], acc[i][j], 0, 0, 0);
    };

    stage(0, 0);
    stage(1, 1);
#pragma unroll 1
    for (int kt = 0; kt < KDIM / 32 - 1; ++kt) {
      // <=4 outstanding: slice kt's stages done; slice kt+1's stay in flight.
      // (Epilogue stores / atomic of the previous tile only make this wait
      // stricter, never looser -> still correct.)
      asm volatile("s_waitcnt vmcnt(4)" ::: "memory");
      asm volatile("s_barrier" ::: "memory");
      compute(&buf[kt % 3][0]);
      if (kt + 2 < KDIM / 32) stage(kt + 2, (kt + 2) % 3);
    }
    asm volatile("s_waitcnt vmcnt(0)" ::: "memory");
    asm volatile("s_barrier" ::: "memory");
    compute(&buf[(KDIM / 32 - 1) % 3][0]);

    float bj[4];
#pragma unroll
    for (int j = 0; j < 4; ++j) bj[j] = bias[e * NDIM + n0 + wn * 64 + j * 16 + lm];
#pragma unroll
    for (int i = 0; i < 4; ++i)
#pragma unroll
      for (int r = 0; r < 4; ++r) {
        int rabs = tile0 + wm * 64 + i * 16 + lg * 4 + r;   // C/D: row = quad*4 + reg
        if (rabs >= lo && rabs < hi) {
#pragma unroll
          for (int j = 0; j < 4; ++j)
            out[(size_t)rabs * NDIM + n0 + wn * 64 + j * 16 + lm] = acc[i][j][r] + bj[j];
        }
      }
  }
}

// ---------------- round-1 fallback (fp32 in-loop conversion) for small ws ----------------
#define LDA 40
__global__ __launch_bounds__(256) void moe_gemm_kernel(
    const float* __restrict__ x, const int* __restrict__ gs,
    const float* __restrict__ W, const float* __restrict__ bias,
    float* __restrict__ out)
{
  __shared__ __bf16 Al[128 * LDA];
  __shared__ __bf16 Bl[128 * LDA];
  const int e = blockIdx.z, mt = blockIdx.y, nt = blockIdx.x;
  int off = 0;
#pragma unroll
  for (int i = 0; i < NEXP; ++i) { int g = gs[i]; if (i < e) off += g; }
  const int ge = gs[e];
  const int m0 = mt * 128;
  if (m0 >= ge) return;
  const int rows = min(128, ge - m0);
  const int row0 = off + m0;
  const int n0 = nt * 128;
  const int t = threadIdx.x, lane = t & 63, wv = t >> 6;
  const int wm = wv & 1, wn = wv >> 1, lm = lane & 15, lg = lane >> 4;
  const int am = t >> 3, kq = t & 7, nb = t & 127, kh = t >> 7;
  float4 aReg[4]; float bReg[16];
  const float* Wp = W + (size_t)e * KDIM * NDIM + n0 + nb;
  auto load_tile = [&](int kt) {
#pragma unroll
    for (int p = 0; p < 4; ++p) {
      int r = am + 32 * p;
      if (r < rows) aReg[p] = *(const float4*)(x + (size_t)(row0 + r) * KDIM + kt * 32 + kq * 4);
      else aReg[p] = make_float4(0.f, 0.f, 0.f, 0.f);
    }
    const float* wp = Wp + (size_t)(kt * 32 + kh * 16) * NDIM;
#pragma unroll
    for (int j = 0; j < 16; ++j) bReg[j] = wp[(size_t)j * NDIM];
  };
  auto store_tile = [&]() {
#pragma unroll
    for (int p = 0; p < 4; ++p) {
      bf16x4 v;
      v[0] = (__bf16)aReg[p].x; v[1] = (__bf16)aReg[p].y;
      v[2] = (__bf16)aReg[p].z; v[3] = (__bf16)aReg[p].w;
      *(bf16x4*)(Al + (am + 32 * p) * LDA + kq * 4) = v;
    }
    bf16x8 b0, b1;
#pragma unroll
    for (int j = 0; j < 8; ++j) { b0[j] = (__bf16)bReg[j]; b1[j] = (__bf16)bReg[8 + j]; }
    *(bf16x8*)(Bl + nb * LDA + kh * 16) = b0;
    *(bf16x8*)(Bl + nb * LDA + kh * 16 + 8) = b1;
  };
  f32x4 acc[4][4] = {};
  load_tile(0);
#pragma unroll 1
  for (int kt = 0; kt < KDIM / 32; ++kt) {
    __syncthreads();
    store_tile();
    __syncthreads();
    if (kt + 1 < KDIM / 32) load_tile(kt + 1);
    bf16x8 af[4], bfr[4];
#pragma unroll
    for (int i = 0; i < 4; ++i)
      af[i] = *(const bf16x8*)(Al + (wm * 64 + i * 16 + lm) * LDA + lg * 8);
#pragma unroll
    for (int j = 0; j < 4; ++j)
      bfr[j] = *(const bf16x8*)(Bl + (wn * 64 + j * 16 + lm) * LDA + lg * 8);
#pragma unroll
    for (int i = 0; i < 4; ++i)
#pragma unroll
      for (int j = 0; j < 4; ++j)
        acc[i][j] = __builtin_amdgcn_mfma_f32_16x16x32_bf16(af[i], bfr[j], acc[i][j], 0, 0, 0);
  }
  float bj[4];
#pragma unroll
  for (int j = 0; j < 4; ++j) bj[j] = bias[e * NDIM + n0 + wn * 64 + j * 16 + lm];
#pragma unroll
  for (int i = 0; i < 4; ++i)
#pragma unroll
    for (int r = 0; r < 4; ++r) {
      int rr = wm * 64 + i * 16 + lg * 4 + r;
      if (rr < rows) {
#pragma unroll
        for (int j = 0; j < 4; ++j)
          out[(size_t)(row0 + rr) * NDIM + n0 + wn * 64 + j * 16 + lm] = acc[i][j][r] + bj[j];
      }
    }
}

extern "C" void kernel_launch(void* const* d_in, const int* in_sizes, int n_in,
                              void* d_out, int out_size, void* d_ws, size_t ws_size,
                              hipStream_t stream) {
  const float* x    = (const float*)d_in[0];
  const int*   gs   = (const int*)d_in[1];
  const float* W    = (const float*)d_in[2];
  const float* bias = (const float*)d_in[3];
  float*       out  = (float*)d_out;

  const size_t swA_bytes = (size_t)TTOK * KDIM * 2;
  const size_t swB_bytes = (size_t)NEXP * KDIM * NDIM * 2;
  if (ws_size >= swA_bytes + swB_bytes + 256) {
    __bf16* swA = (__bf16*)d_ws;
    __bf16* swB = (__bf16*)((char*)d_ws + swA_bytes);
    int*    ctr = (int*)((char*)d_ws + swA_bytes + swB_bytes);
    prepass<<<dim3(1024 + 2048), 256, 0, stream>>>(x, W, swA, swB, ctr);
    moe_gemm_persist<<<dim3(512), 256, 0, stream>>>(swA, swB, gs, bias, out, ctr);
  } else {
    moe_gemm_kernel<<<dim3(NDIM / 128, TTOK / 128, NEXP), 256, 0, stream>>>(x, gs, W, bias, out);
  }
}